// Round 8
// baseline (4613.904 us; speedup 1.0000x reference)
//
#include <hip/hip_runtime.h>

// Portfolio PGD: B=4096 batches, n=104 assets.
// R7: 2 waves (128 thr) per batch; lane owns ONE Sigma row (52 v2h = 52
// VGPRs, fp16) -> ~80 VGPR total -> 6 waves/SIMD cap, 2x resident waves,
// half the per-iter serial chain vs R5. Matvec: 52 v_dot2_f32_f16 in 4
// independent chains, x broadcast via uniform-address LDS ds_read_b128.
// Block-global reductions: per-wave DPP partial (no readlane, no ballot)
// -> lane63 ds_write -> 1 barrier -> uniform LDS read; dual-channel
// {sum,count} in one call. Michelot warm-started fixed point (exact).

#define NASSET 104
#define POWER_ITERS 20
#define N_ITERS 300
#define RPW 52  // rows per wave

typedef _Float16 v2h __attribute__((ext_vector_type(2)));

template <int CTRL, int ROW_MASK>
__device__ __forceinline__ float dppf(float x) {
  return __int_as_float(__builtin_amdgcn_update_dpp(
      0, __float_as_int(x), CTRL, ROW_MASK, 0xf, true));
}

// Wave-local sum; total lands in lane 63. Pure VALU pipe, no readlane.
__device__ __forceinline__ float wsum63(float x) {
  x += dppf<0x111, 0xf>(x);  // row_shr:1
  x += dppf<0x112, 0xf>(x);  // row_shr:2
  x += dppf<0x114, 0xf>(x);  // row_shr:4
  x += dppf<0x118, 0xf>(x);  // row_shr:8
  x += dppf<0x142, 0xa>(x);  // row_bcast15
  x += dppf<0x143, 0xc>(x);  // row_bcast31 -> lane63 = wave total
  return x;
}

// Block-global dual reduction (2 waves). One barrier; results broadcast
// via uniform LDS reads. Alternating slots (ph) make back-to-back calls
// WAR-safe: write_{n+2} is after barrier_{n+1}, which is after read_n.
__device__ __forceinline__ void bred2(float a, float b, int lane, int wv,
                                      float *red, int &ph, float &A,
                                      float &B) {
  a = wsum63(a);
  b = wsum63(b);
  if (lane == 63) {
    red[ph * 4 + wv * 2 + 0] = a;
    red[ph * 4 + wv * 2 + 1] = b;
  }
  __syncthreads();
  A = red[ph * 4 + 0] + red[ph * 4 + 2];
  B = red[ph * 4 + 1] + red[ph * 4 + 3];
  ph ^= 1;
}

__global__ __launch_bounds__(128, 6) void pgd_qp_kernel(
    const float *__restrict__ returns, const float *__restrict__ cov,
    float *__restrict__ out, int B) {
  const int b = blockIdx.x;
  if (b >= B) return;
  const int tid = (int)threadIdx.x;
  const int wv = tid >> 6, lane = tid & 63;
  const int row = wv * RPW + lane;  // valid if lane < RPW
  const bool okr = (lane < RPW);
  const int rowc = okr ? row : (wv * RPW + RPW - 1);

  __shared__ __align__(16) _Float16 xs[NASSET];  // x broadcast (104 fp16)
  __shared__ float red[8];                       // dual-slot reduction buf
  int ph = 0;

  const float *Cb = cov + (size_t)b * NASSET * NASSET;
  const float mu = returns[(size_t)b * NASSET + rowc];

  // ---- Load + symmetrize one Sigma row -> 52 packed fp16 regs ----
  // S[i][j] = 0.5*(C[i][j] + C[j][i]) + (i==j)*1e-6   (RISK_AVERSION==1)
  v2h S[RPW];
#pragma unroll
  for (int q = 0; q < NASSET / 4; ++q) {
    const float4 p = *reinterpret_cast<const float4 *>(Cb + (size_t)rowc * NASSET + 4 * q);
    float sv[4];
#pragma unroll
    for (int u = 0; u < 4; ++u) {
      const int j = 4 * q + u;
      const float cp = Cb[(size_t)j * NASSET + rowc];  // coalesced over lanes
      const float pu = (u == 0) ? p.x : (u == 1) ? p.y : (u == 2) ? p.z : p.w;
      sv[u] = 0.5f * (pu + cp) + ((j == rowc) ? 1e-6f : 0.f);
    }
    S[2 * q] = (v2h){(_Float16)sv[0], (_Float16)sv[1]};
    S[2 * q + 1] = (v2h){(_Float16)sv[2], (_Float16)sv[3]};
  }

  // y = (S x)[row]: 52 dot2 in 4 independent chains, x from uniform LDS.
#define MATVEC(ydst)                                                     \
  {                                                                      \
    float ca = 0.f, cb = 0.f, cc = 0.f, cd = 0.f;                        \
    _Pragma("unroll") for (int i = 0; i < 13; ++i) {                     \
      const uint4 q4 = *reinterpret_cast<const uint4 *>(xs + 8 * i);     \
      ca = __builtin_amdgcn_fdot2(S[4 * i + 0],                          \
                                  __builtin_bit_cast(v2h, q4.x), ca, false); \
      cb = __builtin_amdgcn_fdot2(S[4 * i + 1],                          \
                                  __builtin_bit_cast(v2h, q4.y), cb, false); \
      cc = __builtin_amdgcn_fdot2(S[4 * i + 2],                          \
                                  __builtin_bit_cast(v2h, q4.z), cc, false); \
      cd = __builtin_amdgcn_fdot2(S[4 * i + 3],                          \
                                  __builtin_bit_cast(v2h, q4.w), cd, false); \
    }                                                                    \
    ydst = (ca + cb) + (cc + cd);                                        \
  }

  // ---- Power iteration for lambda_max ----
  const float inv_n = 1.0f / (float)NASSET;
  float v = okr ? inv_n : 0.f;  // v[row] per lane
#pragma unroll 1
  for (int pi = 0; pi < POWER_ITERS; ++pi) {
    if (okr) xs[row] = (_Float16)v;
    __syncthreads();
    float y;
    MATVEC(y);
    const float ym = okr ? y : 0.f;
    float n2, dmy;
    bred2(ym * ym, 0.f, lane, wv, red, ph, n2, dmy);
    const float inv = 1.0f / (sqrtf(n2) + 1e-12f);
    v = ym * inv;
  }
  float lam;
  {
    if (okr) xs[row] = (_Float16)v;
    __syncthreads();
    float z;
    MATVEC(z);
    float dmy;
    bred2(v * (okr ? z : 0.f), 0.f, lane, wv, red, ph, lam, dmy);
  }
  const float eta = 1.0f / (2.2f * lam + 1e-8f);

  // Folded gradient constants: t = fma(-2eta, Sw, w + eta*mu)
  const float ne2 = -2.0f * eta;
  const float em = eta * mu;

  // ---- Projected gradient descent ----
  float w = okr ? inv_n : 0.f;
  float theta_ws = 0.f;
#pragma unroll 1
  for (int it = 0; it < N_ITERS; ++it) {
    if (okr) xs[row] = (_Float16)w;
    __syncthreads();
    float y;
    MATVEC(y);
    const float t = okr ? fmaf(ne2, y, w + em) : -1e30f;

    // Michelot fixed point: theta = (sum_{t>theta} t - 1)/k; converges to
    // the unique theta* from ANY start -> warm start across iters is exact.
    float theta = theta_ws;
    if (it == 0) {
      float sa, dmy;
      bred2(okr ? t : 0.f, 0.f, lane, wv, red, ph, sa, dmy);
      theta = (sa - 1.0f) * inv_n;
    }
    int kp = -1;
#pragma unroll 1
    for (int r = 0; r < 32; ++r) {
      const bool c = t > theta;  // invalid lanes: t=-1e30 -> false
      float s2, kf;
      bred2(c ? t : 0.f, c ? 1.f : 0.f, lane, wv, red, ph, s2, kf);
      const int k = (int)kf;  // exact: integer-valued sums <= 104
      if (k == kp) break;     // active set stable -> fixed point (uniform)
      if (k == 0) {           // warm start above max(t): cold restart
        float sa, dmy;
        bred2(okr ? t : 0.f, 0.f, lane, wv, red, ph, sa, dmy);
        theta = (sa - 1.0f) * inv_n;
        kp = -1;
        continue;
      }
      theta = (s2 - 1.0f) * __builtin_amdgcn_rcpf(kf);
      kp = k;
    }
    theta_ws = theta;
    w = okr ? fmaxf(t - theta, 0.f) : 0.f;
  }

  // ---- Store ----
  if (okr) out[(size_t)b * NASSET + row] = w;
}

extern "C" void kernel_launch(void *const *d_in, const int *in_sizes, int n_in,
                              void *d_out, int out_size, void *d_ws,
                              size_t ws_size, hipStream_t stream) {
  const float *returns = (const float *)d_in[0];
  const float *cov = (const float *)d_in[1];
  float *out = (float *)d_out;
  const int B = in_sizes[0] / NASSET;  // 4096
  pgd_qp_kernel<<<dim3(B), dim3(128), 0, stream>>>(returns, cov, out, B);
}

// Round 9
// 790.645 us; speedup vs baseline: 5.8356x; 5.8356x over previous
//
#include <hip/hip_runtime.h>

// Portfolio PGD: B=4096 batches, n=104 assets.
// R8 = R7 structure with launch_bounds(128,4): R7's (128,6) capped VGPRs
// at ~85 and the compiler spilled the entire S[52] row array to scratch
// (VGPR=40, FETCH 8.3GB, 4.6ms). Budget 128 VGPRs -> S stays resident;
// natural occupancy ~5-6 waves/SIMD.
// 2 waves (128 thr) per batch; lane owns ONE Sigma row (52 v2h, fp16).
// Matvec: 52 v_dot2_f32_f16 in 4 chains, x via uniform-address LDS reads.
// Block reductions: DPP partial -> lane63 ds_write -> 1 barrier -> uniform
// read; dual-channel {sum,count}. Michelot warm-started fixed point.

#define NASSET 104
#define POWER_ITERS 20
#define N_ITERS 300
#define RPW 52  // rows per wave

typedef _Float16 v2h __attribute__((ext_vector_type(2)));

template <int CTRL, int ROW_MASK>
__device__ __forceinline__ float dppf(float x) {
  return __int_as_float(__builtin_amdgcn_update_dpp(
      0, __float_as_int(x), CTRL, ROW_MASK, 0xf, true));
}

// Wave-local sum; total lands in lane 63. Pure VALU pipe, no readlane.
__device__ __forceinline__ float wsum63(float x) {
  x += dppf<0x111, 0xf>(x);  // row_shr:1
  x += dppf<0x112, 0xf>(x);  // row_shr:2
  x += dppf<0x114, 0xf>(x);  // row_shr:4
  x += dppf<0x118, 0xf>(x);  // row_shr:8
  x += dppf<0x142, 0xa>(x);  // row_bcast15
  x += dppf<0x143, 0xc>(x);  // row_bcast31 -> lane63 = wave total
  return x;
}

// Block-global dual reduction (2 waves). One barrier; results broadcast
// via uniform LDS reads. Alternating slots (ph) make back-to-back calls
// WAR-safe: write_{n+2} is after barrier_{n+1}, which is after read_n.
__device__ __forceinline__ void bred2(float a, float b, int lane, int wv,
                                      float *red, int &ph, float &A,
                                      float &B) {
  a = wsum63(a);
  b = wsum63(b);
  if (lane == 63) {
    red[ph * 4 + wv * 2 + 0] = a;
    red[ph * 4 + wv * 2 + 1] = b;
  }
  __syncthreads();
  A = red[ph * 4 + 0] + red[ph * 4 + 2];
  B = red[ph * 4 + 1] + red[ph * 4 + 3];
  ph ^= 1;
}

__global__ __launch_bounds__(128, 4) void pgd_qp_kernel(
    const float *__restrict__ returns, const float *__restrict__ cov,
    float *__restrict__ out, int B) {
  const int b = blockIdx.x;
  if (b >= B) return;
  const int tid = (int)threadIdx.x;
  const int wv = tid >> 6, lane = tid & 63;
  const int row = wv * RPW + lane;  // valid if lane < RPW
  const bool okr = (lane < RPW);
  const int rowc = okr ? row : (wv * RPW + RPW - 1);

  __shared__ __align__(16) _Float16 xs[NASSET];  // x broadcast (104 fp16)
  __shared__ float red[8];                       // dual-slot reduction buf
  int ph = 0;

  const float *Cb = cov + (size_t)b * NASSET * NASSET;
  const float mu = returns[(size_t)b * NASSET + rowc];

  // ---- Load + symmetrize one Sigma row -> 52 packed fp16 regs ----
  // S[i][j] = 0.5*(C[i][j] + C[j][i]) + (i==j)*1e-6   (RISK_AVERSION==1)
  v2h S[RPW];
#pragma unroll
  for (int q = 0; q < NASSET / 4; ++q) {
    const float4 p = *reinterpret_cast<const float4 *>(Cb + (size_t)rowc * NASSET + 4 * q);
    float sv[4];
#pragma unroll
    for (int u = 0; u < 4; ++u) {
      const int j = 4 * q + u;
      const float cp = Cb[(size_t)j * NASSET + rowc];  // coalesced over lanes
      const float pu = (u == 0) ? p.x : (u == 1) ? p.y : (u == 2) ? p.z : p.w;
      sv[u] = 0.5f * (pu + cp) + ((j == rowc) ? 1e-6f : 0.f);
    }
    S[2 * q] = (v2h){(_Float16)sv[0], (_Float16)sv[1]};
    S[2 * q + 1] = (v2h){(_Float16)sv[2], (_Float16)sv[3]};
  }

  // y = (S x)[row]: 52 dot2 in 4 independent chains, x from uniform LDS.
#define MATVEC(ydst)                                                     \
  {                                                                      \
    float ca = 0.f, cb = 0.f, cc = 0.f, cd = 0.f;                        \
    _Pragma("unroll") for (int i = 0; i < 13; ++i) {                     \
      const uint4 q4 = *reinterpret_cast<const uint4 *>(xs + 8 * i);     \
      ca = __builtin_amdgcn_fdot2(S[4 * i + 0],                          \
                                  __builtin_bit_cast(v2h, q4.x), ca, false); \
      cb = __builtin_amdgcn_fdot2(S[4 * i + 1],                          \
                                  __builtin_bit_cast(v2h, q4.y), cb, false); \
      cc = __builtin_amdgcn_fdot2(S[4 * i + 2],                          \
                                  __builtin_bit_cast(v2h, q4.z), cc, false); \
      cd = __builtin_amdgcn_fdot2(S[4 * i + 3],                          \
                                  __builtin_bit_cast(v2h, q4.w), cd, false); \
    }                                                                    \
    ydst = (ca + cb) + (cc + cd);                                        \
  }

  // ---- Power iteration for lambda_max ----
  const float inv_n = 1.0f / (float)NASSET;
  float v = okr ? inv_n : 0.f;  // v[row] per lane
#pragma unroll 1
  for (int pi = 0; pi < POWER_ITERS; ++pi) {
    if (okr) xs[row] = (_Float16)v;
    __syncthreads();
    float y;
    MATVEC(y);
    const float ym = okr ? y : 0.f;
    float n2, dmy;
    bred2(ym * ym, 0.f, lane, wv, red, ph, n2, dmy);
    const float inv = 1.0f / (sqrtf(n2) + 1e-12f);
    v = ym * inv;
  }
  float lam;
  {
    if (okr) xs[row] = (_Float16)v;
    __syncthreads();
    float z;
    MATVEC(z);
    float dmy;
    bred2(v * (okr ? z : 0.f), 0.f, lane, wv, red, ph, lam, dmy);
  }
  const float eta = 1.0f / (2.2f * lam + 1e-8f);

  // Folded gradient constants: t = fma(-2eta, Sw, w + eta*mu)
  const float ne2 = -2.0f * eta;
  const float em = eta * mu;

  // ---- Projected gradient descent ----
  float w = okr ? inv_n : 0.f;
  float theta_ws = 0.f;
#pragma unroll 1
  for (int it = 0; it < N_ITERS; ++it) {
    if (okr) xs[row] = (_Float16)w;
    __syncthreads();
    float y;
    MATVEC(y);
    const float t = okr ? fmaf(ne2, y, w + em) : -1e30f;

    // Michelot fixed point: theta = (sum_{t>theta} t - 1)/k; converges to
    // the unique theta* from ANY start -> warm start across iters is exact.
    float theta = theta_ws;
    if (it == 0) {
      float sa, dmy;
      bred2(okr ? t : 0.f, 0.f, lane, wv, red, ph, sa, dmy);
      theta = (sa - 1.0f) * inv_n;
    }
    int kp = -1;
#pragma unroll 1
    for (int r = 0; r < 32; ++r) {
      const bool c = t > theta;  // invalid lanes: t=-1e30 -> false
      float s2, kf;
      bred2(c ? t : 0.f, c ? 1.f : 0.f, lane, wv, red, ph, s2, kf);
      const int k = (int)kf;  // exact: integer-valued sums <= 104
      if (k == kp) break;     // active set stable -> fixed point (uniform)
      if (k == 0) {           // warm start above max(t): cold restart
        float sa, dmy;
        bred2(okr ? t : 0.f, 0.f, lane, wv, red, ph, sa, dmy);
        theta = (sa - 1.0f) * inv_n;
        kp = -1;
        continue;
      }
      theta = (s2 - 1.0f) * __builtin_amdgcn_rcpf(kf);
      kp = k;
    }
    theta_ws = theta;
    w = okr ? fmaxf(t - theta, 0.f) : 0.f;
  }

  // ---- Store ----
  if (okr) out[(size_t)b * NASSET + row] = w;
}

extern "C" void kernel_launch(void *const *d_in, const int *in_sizes, int n_in,
                              void *d_out, int out_size, void *d_ws,
                              size_t ws_size, hipStream_t stream) {
  const float *returns = (const float *)d_in[0];
  const float *cov = (const float *)d_in[1];
  float *out = (float *)d_out;
  const int B = in_sizes[0] / NASSET;  // 4096
  pgd_qp_kernel<<<dim3(B), dim3(128), 0, stream>>>(returns, cov, out, B);
}

// Round 10
// 487.838 us; speedup vs baseline: 9.4579x; 1.6207x over previous
//
#include <hip/hip_runtime.h>

// Portfolio PGD: B=4096 batches, n=104 assets.
// R9 = R5 structure (best: 492us) + PINNED register budget.
// R5/R8 counter forensics: compiler reported VGPR=64 while S needs 104
// regs -> it spilled/AGPR'd Sigma chasing occupancy (WRITE_SIZE 5760/9856
// vs 1664 floor), roughly doubling per-iter VALU work with copy traffic.
// amdgpu_waves_per_eu(3,3) pins exactly 3 waves/EU -> 170 VGPR budget ->
// S[104] fully resident, no spill. Grid only supplies 4 waves/SIMD, so
// the occupancy cost vs R5's measured 35% is nil.
// 1 wave per batch. Thread l owns Sigma rows l and 64+l in packed fp16.
// Matvec: 104 v_dot2_f32_f16 fed by uniform-address LDS ds_read_b128.
// Reductions: GCN DPP row_shr/row_bcast idiom. Michelot warm-started.

#define NASSET 104
#define POWER_ITERS 20
#define N_ITERS 300

typedef _Float16 v2h __attribute__((ext_vector_type(2)));

__device__ __forceinline__ float readl(float x, int lane) {
  return __uint_as_float(__builtin_amdgcn_readlane(__float_as_uint(x), lane));
}

template <int CTRL, int ROW_MASK>
__device__ __forceinline__ float dppf(float x) {
  return __int_as_float(__builtin_amdgcn_update_dpp(
      0, __float_as_int(x), CTRL, ROW_MASK, 0xf, true));
}

// Full-wave (64-lane) sum, broadcast to all lanes via SGPR. Pure VALU pipe.
__device__ __forceinline__ float wsum(float x) {
  x += dppf<0x111, 0xf>(x);  // row_shr:1
  x += dppf<0x112, 0xf>(x);  // row_shr:2
  x += dppf<0x114, 0xf>(x);  // row_shr:4
  x += dppf<0x118, 0xf>(x);  // row_shr:8  -> lane15 of each row = row sum
  x += dppf<0x142, 0xa>(x);  // row_bcast15 into rows 1,3
  x += dppf<0x143, 0xc>(x);  // row_bcast31 into rows 2,3 -> lane63 = total
  return readl(x, 63);
}

// y[r] = sum_j S[r][j]*x[j]; Sigma fp16-packed, x broadcast from LDS (fp16).
__device__ __forceinline__ void matvec104(const v2h (&SA)[52],
                                          const v2h (&SB)[52],
                                          const _Float16 *__restrict__ xs,
                                          float &y0, float &y1) {
  float a0 = 0.f, b0 = 0.f, a1 = 0.f, b1 = 0.f;  // 2 chains/row (latency)
#pragma unroll
  for (int i = 0; i < 13; ++i) {
    const uint4 q = *reinterpret_cast<const uint4 *>(xs + 8 * i);
    const v2h x0 = __builtin_bit_cast(v2h, q.x);
    const v2h x1 = __builtin_bit_cast(v2h, q.y);
    const v2h x2 = __builtin_bit_cast(v2h, q.z);
    const v2h x3 = __builtin_bit_cast(v2h, q.w);
    a0 = __builtin_amdgcn_fdot2(SA[4 * i + 0], x0, a0, false);
    a1 = __builtin_amdgcn_fdot2(SB[4 * i + 0], x0, a1, false);
    b0 = __builtin_amdgcn_fdot2(SA[4 * i + 1], x1, b0, false);
    b1 = __builtin_amdgcn_fdot2(SB[4 * i + 1], x1, b1, false);
    a0 = __builtin_amdgcn_fdot2(SA[4 * i + 2], x2, a0, false);
    a1 = __builtin_amdgcn_fdot2(SB[4 * i + 2], x2, a1, false);
    b0 = __builtin_amdgcn_fdot2(SA[4 * i + 3], x3, b0, false);
    b1 = __builtin_amdgcn_fdot2(SB[4 * i + 3], x3, b1, false);
  }
  y0 = a0 + b0;
  y1 = a1 + b1;
}

__global__ __attribute__((amdgpu_flat_work_group_size(64, 64),
                          amdgpu_waves_per_eu(3, 3))) void pgd_qp_kernel(
    const float *__restrict__ returns, const float *__restrict__ cov,
    float *__restrict__ out, int B) {
  const int b = blockIdx.x;
  if (b >= B) return;
  const int l = (int)threadIdx.x;
  const int r0 = l;
  const int r1 = 64 + l;
  const bool ok1 = (r1 < NASSET);
  const int r1c = ok1 ? r1 : (NASSET - 1);

  __shared__ __align__(16) _Float16 xs[128];  // x broadcast buffer (fp16)

  const float *Cb = cov + (size_t)b * NASSET * NASSET;
  const float mu0 = returns[(size_t)b * NASSET + r0];
  const float mu1 = returns[(size_t)b * NASSET + r1c];

  // ---- Load + symmetrize Sigma rows -> packed fp16 registers ----
  // S[i][j] = 0.5*(C[i][j] + C[j][i]) + (i==j)*1e-6   (RISK_AVERSION==1)
  v2h SA[52], SB[52];
#pragma unroll
  for (int q = 0; q < NASSET / 4; ++q) {
    const float4 ra = *reinterpret_cast<const float4 *>(Cb + (size_t)r0 * NASSET + q * 4);
    const float4 rb = *reinterpret_cast<const float4 *>(Cb + (size_t)r1c * NASSET + q * 4);
    float sa[4], sb[4];
#pragma unroll
    for (int u = 0; u < 4; ++u) {
      const int j = q * 4 + u;
      const float ca = Cb[(size_t)j * NASSET + r0];   // coalesced across lanes
      const float cb = Cb[(size_t)j * NASSET + r1c];
      const float rau = (u == 0) ? ra.x : (u == 1) ? ra.y : (u == 2) ? ra.z : ra.w;
      const float rbu = (u == 0) ? rb.x : (u == 1) ? rb.y : (u == 2) ? rb.z : rb.w;
      sa[u] = 0.5f * (rau + ca) + ((j == r0) ? 1e-6f : 0.f);
      sb[u] = 0.5f * (rbu + cb) + ((j == r1c) ? 1e-6f : 0.f);
    }
    SA[2 * q] = (v2h){(_Float16)sa[0], (_Float16)sa[1]};
    SA[2 * q + 1] = (v2h){(_Float16)sa[2], (_Float16)sa[3]};
    SB[2 * q] = (v2h){(_Float16)sb[0], (_Float16)sb[1]};
    SB[2 * q + 1] = (v2h){(_Float16)sb[2], (_Float16)sb[3]};
  }

  // ---- Power iteration for lambda_max ----
  const float inv_n = 1.0f / (float)NASSET;
  float v0 = inv_n, v1 = ok1 ? inv_n : 0.f;
#pragma unroll 1
  for (int pi = 0; pi < POWER_ITERS; ++pi) {
    xs[l] = (_Float16)v0;
    xs[64 + l] = (_Float16)v1;  // cols 104..127 stay 0 (v1==0 when !ok1)
    __syncthreads();
    float y0, y1;
    matvec104(SA, SB, xs, y0, y1);
    y1 = ok1 ? y1 : 0.f;
    const float n2 = wsum(y0 * y0 + y1 * y1);
    const float inv = 1.0f / (sqrtf(n2) + 1e-12f);
    v0 = y0 * inv;
    v1 = ok1 ? (y1 * inv) : 0.f;
  }
  {
    xs[l] = (_Float16)v0;
    xs[64 + l] = (_Float16)v1;
    __syncthreads();
  }
  float z0, z1;
  matvec104(SA, SB, xs, z0, z1);
  z1 = ok1 ? z1 : 0.f;
  const float lam = wsum(v0 * z0 + v1 * z1);
  const float eta = 1.0f / (2.2f * lam + 1e-8f);

  // Folded gradient constants: t = fma(-2eta, Sw, w + eta*mu)
  const float ne2 = -2.0f * eta;
  const float em0 = eta * mu0;
  const float em1 = eta * mu1;

  // ---- Projected gradient descent ----
  float w0 = inv_n, w1 = ok1 ? inv_n : 0.f;
  float theta_ws = 0.f;  // warm-start threshold carried across iterations
#pragma unroll 1
  for (int it = 0; it < N_ITERS; ++it) {
    xs[l] = (_Float16)w0;
    xs[64 + l] = (_Float16)w1;
    __syncthreads();
    float y0, y1;
    matvec104(SA, SB, xs, y0, y1);
    const float t0 = fmaf(ne2, y0, w0 + em0);
    const float t1 = ok1 ? fmaf(ne2, y1, w1 + em1) : -1e30f;

    // Michelot fixed point: theta = (sum_{t>theta} t - 1)/k. The map
    // converges monotonically to the unique theta* from ANY start, so
    // warm-starting from the previous iteration's theta is exact.
    float theta = (it == 0)
                      ? (wsum(t0 + (ok1 ? t1 : 0.f)) - 1.0f) * inv_n
                      : theta_ws;
    int kp = -1;
#pragma unroll 1
    for (int r = 0; r < 32; ++r) {
      const bool c0 = t0 > theta;
      const bool c1 = t1 > theta;  // t1 = -1e30 on invalid lanes -> false
      const float s2 = wsum((c0 ? t0 : 0.f) + (c1 ? t1 : 0.f));
      const int k = __popcll(__ballot(c0)) + __popcll(__ballot(c1));
      if (k == kp) break;  // active set stable -> theta is the fixed point
      if (k == 0) {        // warm start above max(t): cold restart (rare)
        theta = (wsum(t0 + (ok1 ? t1 : 0.f)) - 1.0f) * inv_n;
        kp = -1;
        continue;
      }
      theta = (s2 - 1.0f) * __builtin_amdgcn_rcpf((float)k);
      kp = k;
    }
    theta_ws = theta;
    w0 = fmaxf(t0 - theta, 0.f);
    w1 = ok1 ? fmaxf(t1 - theta, 0.f) : 0.f;
  }

  // ---- Store ----
  out[(size_t)b * NASSET + r0] = w0;
  if (ok1) out[(size_t)b * NASSET + r1] = w1;
}

extern "C" void kernel_launch(void *const *d_in, const int *in_sizes, int n_in,
                              void *d_out, int out_size, void *d_ws,
                              size_t ws_size, hipStream_t stream) {
  const float *returns = (const float *)d_in[0];
  const float *cov = (const float *)d_in[1];
  float *out = (float *)d_out;
  const int B = in_sizes[0] / NASSET;  // 4096
  pgd_qp_kernel<<<dim3(B), dim3(64), 0, stream>>>(returns, cov, out, B);
}